// Round 3
// baseline (139.469 us; speedup 1.0000x reference)
//
#include <hip/hip_runtime.h>
#include <hip/hip_bf16.h>
#include <cstddef>

// Problem constants (match reference)
static constexpr int Bdim = 32;
static constexpr int Edim = 256;
static constexpr int Cdim = 7;
static constexpr int Ddim = 256;

// Precomputed fused tables, 101 rows of 256 floats:
// rows  0..52 : cardP  = card_table   @ Wc[   0: 256]
// rows 53..61 : heroP  = hero_table   @ Wc[ 256: 512]
// rows 62..70 : actP   = acting_table @ Wc[ 512: 768]
// rows 71..80 : numP   = nump_table   @ Wc[ 768:1024]
// rows 81..82 : WsP    = W_scalar     @ Wc[1024:1280]
// rows 83..91 : WbP    = W_bet        @ Wc[1280:1536]
// rows 92..99 : WaP    = W_action     @ Wc[1536:1792]
// row  100    : bP     = b_combine + b_scalar@Wc4 + b_bet@Wc5 + b_action@Wc6
__device__ float g_tabs[101 * Ddim];

// Stage A: 101 rows x 8 K-chunks = 808 blocks of 256 threads. Each block
// computes a 32-deep partial dot for all 256 outputs of one row. src values
// are wave-uniform (scalar loads); W loads are fully coalesced. Partials go
// to d_ws. 808 blocks -> ~3 blocks/CU across all 256 CUs (vs 101 before).
__global__ __launch_bounds__(256) void precompute_partial(
    const float* __restrict__ card_table,
    const float* __restrict__ hero_table,
    const float* __restrict__ acting_table,
    const float* __restrict__ nump_table,
    const float* __restrict__ W_scalar, const float* __restrict__ b_scalar,
    const float* __restrict__ W_bet,    const float* __restrict__ b_bet,
    const float* __restrict__ W_action, const float* __restrict__ b_action,
    const float* __restrict__ W_combine,
    float* __restrict__ partials)
{
    const int r  = blockIdx.x >> 3;   // 0..100
    const int kc = blockIdx.x & 7;    // 0..7
    const int d  = threadIdx.x;       // 0..255
    float acc = 0.0f;

    if (r < 100) {
        const float* srcp;
        int off;
        if      (r < 53) { srcp = card_table   + (size_t)r        * Ddim; off = 0;    }
        else if (r < 62) { srcp = hero_table   + (size_t)(r - 53) * Ddim; off = 256;  }
        else if (r < 71) { srcp = acting_table + (size_t)(r - 62) * Ddim; off = 512;  }
        else if (r < 81) { srcp = nump_table   + (size_t)(r - 71) * Ddim; off = 768;  }
        else if (r < 83) { srcp = W_scalar     + (size_t)(r - 81) * Ddim; off = 1024; }
        else if (r < 92) { srcp = W_bet        + (size_t)(r - 83) * Ddim; off = 1280; }
        else             { srcp = W_action     + (size_t)(r - 92) * Ddim; off = 1536; }
        const int k0 = kc << 5;       // kc * 32
        const float* w = W_combine + ((size_t)off + k0) * Ddim + d;
        #pragma unroll
        for (int k = 0; k < 32; ++k)
            acc = fmaf(srcp[k0 + k], w[(size_t)k * Ddim], acc);
    } else {
        // fused bias row: concatenated K space q in [0,768):
        //   q<256 -> b_scalar[q]; q<512 -> b_bet[q-256]; else b_action[q-512]
        const int q0 = kc * 96;
        #pragma unroll
        for (int q = q0; q < q0 + 96; ++q) {
            const float s = (q < 256) ? b_scalar[q]
                          : (q < 512) ? b_bet[q - 256]
                                      : b_action[q - 512];
            acc = fmaf(s, W_combine[(size_t)(1024 + q) * Ddim + d], acc);
        }
    }
    partials[(size_t)blockIdx.x * Ddim + d] = acc;
}

// Stage B: sum the 8 partials per (r, d), fold b_combine into the bias row.
__global__ __launch_bounds__(256) void precompute_reduce(
    const float* __restrict__ partials,
    const float* __restrict__ b_combine)
{
    const int r = blockIdx.x;
    const int d = threadIdx.x;
    float v = 0.0f;
    #pragma unroll
    for (int kc = 0; kc < 8; ++kc)
        v += partials[(size_t)(r * 8 + kc) * Ddim + d];
    if (r == 100) v += b_combine[d];
    g_tabs[(size_t)r * Ddim + d] = v;
}

__device__ __forceinline__ float4 ld4(const float* p) {
    return *reinterpret_cast<const float4*>(p);
}
__device__ __forceinline__ void add4(float4& a, const float4 b) {
    a.x += b.x; a.y += b.y; a.z += b.z; a.w += b.w;
}
__device__ __forceinline__ void fma4(float4& a, const float s, const float4 b) {
    a.x = fmaf(s, b.x, a.x);
    a.y = fmaf(s, b.y, a.y);
    a.z = fmaf(s, b.z, a.z);
    a.w = fmaf(s, b.w, a.w);
}

typedef float v4f __attribute__((ext_vector_type(4)));

// One wave (64 lanes) per event; lane holds d = 4*lane .. 4*lane+3 as float4.
// 4 waves per 256-thread block -> grid = 8192/4 = 2048 blocks.
__global__ __launch_bounds__(256) void event_embed(
    const int* __restrict__ card_ids,
    const int* __restrict__ hero_pos,
    const int* __restrict__ acting_pos,
    const int* __restrict__ num_players,
    const int* __restrict__ seq_lengths,
    const float* __restrict__ scalars,
    const float* __restrict__ bets,
    const float* __restrict__ action,
    const float* __restrict__ source_table,
    const float* __restrict__ ln_gamma,
    const float* __restrict__ ln_beta,
    float* __restrict__ out_emb,
    float* __restrict__ out_mask)
{
    const int wave = threadIdx.x >> 6;
    const int lane = threadIdx.x & 63;
    const int g = (blockIdx.x << 2) + wave;   // event index in [0, B*E)
    const int b = g >> 8;                     // E = 256
    const int e = g & 255;
    const int d0 = lane << 2;

    const float* cardP = g_tabs;
    const float* heroP = cardP + 53 * Ddim;
    const float* actP  = heroP +  9 * Ddim;
    const float* numP  = actP  +  9 * Ddim;
    const float* WsP   = numP  + 10 * Ddim;
    const float* WbP   = WsP   +  2 * Ddim;
    const float* WaP   = WbP   +  9 * Ddim;
    const float* bP    = WaP   +  8 * Ddim;

    const float maskf = (e < seq_lengths[b]) ? 1.0f : 0.0f;

    // context vector shared by the event's 7 cards
    float4 ctx = ld4(bP + d0);
    add4(ctx, ld4(heroP + (size_t)hero_pos[g]    * Ddim + d0));
    add4(ctx, ld4(actP  + (size_t)acting_pos[g]  * Ddim + d0));
    add4(ctx, ld4(numP  + (size_t)num_players[g] * Ddim + d0));
    fma4(ctx, scalars[(size_t)g * 2 + 0], ld4(WsP + d0));
    fma4(ctx, scalars[(size_t)g * 2 + 1], ld4(WsP + Ddim + d0));
    #pragma unroll
    for (int j = 0; j < 9; ++j)
        fma4(ctx, bets[(size_t)g * 9 + j], ld4(WbP + j * Ddim + d0));
    #pragma unroll
    for (int j = 0; j < 8; ++j)
        fma4(ctx, action[(size_t)g * 8 + j], ld4(WaP + j * Ddim + d0));

    const float4 gam = ld4(ln_gamma + d0);
    const float4 bta = ld4(ln_beta + d0);
    const float4 s0v = ld4(source_table + d0);          // source id 0 (cards 0..4)
    const float4 s1v = ld4(source_table + Ddim + d0);   // source id 1 (cards 5..6)

    #pragma unroll
    for (int c = 0; c < Cdim; ++c) {
        const int cid = card_ids[(size_t)g * Cdim + c];
        float4 h = ld4(cardP + (size_t)cid * Ddim + d0);
        add4(h, ctx);

        float s  = h.x + h.y + h.z + h.w;
        float sq = h.x * h.x + h.y * h.y + h.z * h.z + h.w * h.w;
        #pragma unroll
        for (int off = 32; off > 0; off >>= 1) {
            s  += __shfl_xor(s,  off, 64);
            sq += __shfl_xor(sq, off, 64);
        }
        const float mean = s * (1.0f / 256.0f);
        const float var  = fmaf(-mean, mean, sq * (1.0f / 256.0f));
        const float inv  = rsqrtf(var + 1e-5f);

        const float4 sv = (c < 5) ? s0v : s1v;
        v4f o;
        o.x = (fmaf((h.x - mean) * inv, gam.x, bta.x) + sv.x) * maskf;
        o.y = (fmaf((h.y - mean) * inv, gam.y, bta.y) + sv.y) * maskf;
        o.z = (fmaf((h.z - mean) * inv, gam.z, bta.z) + sv.z) * maskf;
        o.w = (fmaf((h.w - mean) * inv, gam.w, bta.w) + sv.w) * maskf;
        // write-once 59 MB stream: bypass L2 with non-temporal dwordx4
        __builtin_nontemporal_store(
            o, reinterpret_cast<v4f*>(out_emb + ((size_t)g * Cdim + c) * Ddim + d0));
    }

    if (lane < Cdim)
        out_mask[(size_t)g * Cdim + lane] = maskf;
}

extern "C" void kernel_launch(void* const* d_in, const int* in_sizes, int n_in,
                              void* d_out, int out_size, void* d_ws, size_t ws_size,
                              hipStream_t stream)
{
    (void)in_sizes; (void)n_in; (void)ws_size; (void)out_size;

    const int*   card_ids    = (const int*)d_in[0];
    const int*   hero_pos    = (const int*)d_in[1];
    const int*   acting_pos  = (const int*)d_in[2];
    const int*   num_players = (const int*)d_in[3];
    const int*   seq_lengths = (const int*)d_in[4];
    const float* scalars     = (const float*)d_in[5];
    const float* bets        = (const float*)d_in[6];
    const float* action      = (const float*)d_in[7];
    const float* card_table  = (const float*)d_in[8];
    const float* source_tab  = (const float*)d_in[9];
    const float* hero_table  = (const float*)d_in[10];
    const float* acting_tab  = (const float*)d_in[11];
    const float* nump_table  = (const float*)d_in[12];
    const float* W_scalar    = (const float*)d_in[13];
    const float* b_scalar    = (const float*)d_in[14];
    const float* W_bet       = (const float*)d_in[15];
    const float* b_bet       = (const float*)d_in[16];
    const float* W_action    = (const float*)d_in[17];
    const float* b_action    = (const float*)d_in[18];
    const float* W_combine   = (const float*)d_in[19];
    const float* b_combine   = (const float*)d_in[20];
    const float* ln_gamma    = (const float*)d_in[21];
    const float* ln_beta     = (const float*)d_in[22];

    float* out_emb  = (float*)d_out;
    float* out_mask = out_emb + (size_t)Bdim * Edim * Cdim * Ddim;
    float* partials = (float*)d_ws;              // 808 * 256 floats = 827 KB

    hipLaunchKernelGGL(precompute_partial, dim3(101 * 8), dim3(256), 0, stream,
                       card_table, hero_table, acting_tab, nump_table,
                       W_scalar, b_scalar, W_bet, b_bet, W_action, b_action,
                       W_combine, partials);

    hipLaunchKernelGGL(precompute_reduce, dim3(101), dim3(256), 0, stream,
                       partials, b_combine);

    const int nEvents = Bdim * Edim;             // 8192
    hipLaunchKernelGGL(event_embed, dim3(nEvents / 4), dim3(256), 0, stream,
                       card_ids, hero_pos, acting_pos, num_players, seq_lengths,
                       scalars, bets, action, source_tab, ln_gamma, ln_beta,
                       out_emb, out_mask);
}

// Round 5
// 134.003 us; speedup vs baseline: 1.0408x; 1.0408x over previous
//
#include <hip/hip_runtime.h>
#include <hip/hip_bf16.h>
#include <cstddef>

// Problem constants (match reference)
static constexpr int Bdim = 32;
static constexpr int Edim = 256;
static constexpr int Cdim = 7;
static constexpr int Ddim = 256;

// Precomputed fused tables, 103 rows of 256 floats:
// rows   0..52 : cardP = card_table   @ Wc[   0: 256]
// rows  53..61 : heroP = hero_table   @ Wc[ 256: 512]
// rows  62..70 : actP  = acting_table @ Wc[ 512: 768]
// rows  71..80 : numP  = nump_table   @ Wc[ 768:1024]
// rows  81..82 : WsP   = W_scalar     @ Wc[1024:1280]
// rows  83..91 : WbP   = W_bet        @ Wc[1280:1536]
// rows  92..99 : WaP   = W_action     @ Wc[1536:1792]
// row   100   : b_scalar @ Wc[1024:1280]
// row   101   : b_bet    @ Wc[1280:1536]
// row   102   : b_action @ Wc[1536:1792]
// (b_combine is added in the event kernel — it needs no projection)
__device__ float g_tabs[103 * Ddim];

// One block per row (103 blocks x 256 threads). Thread d computes
// g_tabs[r][d] = sum_k src_r[k] * Wc[off + k][d].
// 4 independent accumulators over 4 K-chunks + unroll-8 -> ~32 outstanding
// coalesced loads per thread (fix for R1's VGPR=8 fully-serialized version).
__global__ __launch_bounds__(256) void precompute_tables(
    const float* __restrict__ card_table,
    const float* __restrict__ hero_table,
    const float* __restrict__ acting_table,
    const float* __restrict__ nump_table,
    const float* __restrict__ W_scalar, const float* __restrict__ b_scalar,
    const float* __restrict__ W_bet,    const float* __restrict__ b_bet,
    const float* __restrict__ W_action, const float* __restrict__ b_action,
    const float* __restrict__ W_combine)
{
    const int r = blockIdx.x;
    const int d = threadIdx.x;

    const float* srcp;
    int off;
    if      (r <  53) { srcp = card_table   + (size_t)r        * Ddim; off = 0;    }
    else if (r <  62) { srcp = hero_table   + (size_t)(r - 53) * Ddim; off = 256;  }
    else if (r <  71) { srcp = acting_table + (size_t)(r - 62) * Ddim; off = 512;  }
    else if (r <  81) { srcp = nump_table   + (size_t)(r - 71) * Ddim; off = 768;  }
    else if (r <  83) { srcp = W_scalar     + (size_t)(r - 81) * Ddim; off = 1024; }
    else if (r <  92) { srcp = W_bet        + (size_t)(r - 83) * Ddim; off = 1280; }
    else if (r < 100) { srcp = W_action     + (size_t)(r - 92) * Ddim; off = 1536; }
    else if (r == 100){ srcp = b_scalar;                               off = 1024; }
    else if (r == 101){ srcp = b_bet;                                  off = 1280; }
    else              { srcp = b_action;                               off = 1536; }

    const float* w = W_combine + (size_t)off * Ddim + d;
    float a0 = 0.f, a1 = 0.f, a2 = 0.f, a3 = 0.f;
    #pragma unroll 8
    for (int k = 0; k < 64; ++k) {
        const float s0 = srcp[k      ];
        const float s1 = srcp[k +  64];
        const float s2 = srcp[k + 128];
        const float s3 = srcp[k + 192];
        a0 = fmaf(s0, w[(size_t)(k      ) * Ddim], a0);
        a1 = fmaf(s1, w[(size_t)(k +  64) * Ddim], a1);
        a2 = fmaf(s2, w[(size_t)(k + 128) * Ddim], a2);
        a3 = fmaf(s3, w[(size_t)(k + 192) * Ddim], a3);
    }
    g_tabs[(size_t)r * Ddim + d] = (a0 + a1) + (a2 + a3);
}

__device__ __forceinline__ float4 ld4(const float* p) {
    return *reinterpret_cast<const float4*>(p);
}
__device__ __forceinline__ void add4(float4& a, const float4 b) {
    a.x += b.x; a.y += b.y; a.z += b.z; a.w += b.w;
}
__device__ __forceinline__ void fma4(float4& a, const float s, const float4 b) {
    a.x = fmaf(s, b.x, a.x);
    a.y = fmaf(s, b.y, a.y);
    a.z = fmaf(s, b.z, a.z);
    a.w = fmaf(s, b.w, a.w);
}

// One wave (64 lanes) per event; lane holds d = 4*lane .. 4*lane+3 as float4.
// 4 waves per 256-thread block -> grid = 8192/4 = 2048 blocks.
__global__ __launch_bounds__(256) void event_embed(
    const int* __restrict__ card_ids,
    const int* __restrict__ hero_pos,
    const int* __restrict__ acting_pos,
    const int* __restrict__ num_players,
    const int* __restrict__ seq_lengths,
    const float* __restrict__ scalars,
    const float* __restrict__ bets,
    const float* __restrict__ action,
    const float* __restrict__ source_table,
    const float* __restrict__ b_combine,
    const float* __restrict__ ln_gamma,
    const float* __restrict__ ln_beta,
    float* __restrict__ out_emb,
    float* __restrict__ out_mask)
{
    const int wave = threadIdx.x >> 6;
    const int lane = threadIdx.x & 63;
    const int g = (blockIdx.x << 2) + wave;   // event index in [0, B*E)
    const int b = g >> 8;                     // E = 256
    const int e = g & 255;
    const int d0 = lane << 2;

    const float* cardP = g_tabs;
    const float* heroP = cardP + 53 * Ddim;
    const float* actP  = heroP +  9 * Ddim;
    const float* numP  = actP  +  9 * Ddim;
    const float* WsP   = numP  + 10 * Ddim;
    const float* WbP   = WsP   +  2 * Ddim;
    const float* WaP   = WbP   +  9 * Ddim;
    const float* bS    = WaP   +  8 * Ddim;   // row 100
    const float* bB    = bS    +      Ddim;   // row 101
    const float* bA    = bB    +      Ddim;   // row 102

    const float maskf = (e < seq_lengths[b]) ? 1.0f : 0.0f;

    // context vector shared by the event's 7 cards
    float4 ctx = ld4(b_combine + d0);
    add4(ctx, ld4(bS + d0));
    add4(ctx, ld4(bB + d0));
    add4(ctx, ld4(bA + d0));
    add4(ctx, ld4(heroP + (size_t)hero_pos[g]    * Ddim + d0));
    add4(ctx, ld4(actP  + (size_t)acting_pos[g]  * Ddim + d0));
    add4(ctx, ld4(numP  + (size_t)num_players[g] * Ddim + d0));
    fma4(ctx, scalars[(size_t)g * 2 + 0], ld4(WsP + d0));
    fma4(ctx, scalars[(size_t)g * 2 + 1], ld4(WsP + Ddim + d0));
    #pragma unroll
    for (int j = 0; j < 9; ++j)
        fma4(ctx, bets[(size_t)g * 9 + j], ld4(WbP + j * Ddim + d0));
    #pragma unroll
    for (int j = 0; j < 8; ++j)
        fma4(ctx, action[(size_t)g * 8 + j], ld4(WaP + j * Ddim + d0));

    const float4 gam = ld4(ln_gamma + d0);
    const float4 bta = ld4(ln_beta + d0);
    const float4 s0v = ld4(source_table + d0);          // source id 0 (cards 0..4)
    const float4 s1v = ld4(source_table + Ddim + d0);   // source id 1 (cards 5..6)

    #pragma unroll
    for (int c = 0; c < Cdim; ++c) {
        const int cid = card_ids[(size_t)g * Cdim + c];
        float4 h = ld4(cardP + (size_t)cid * Ddim + d0);
        add4(h, ctx);

        float s  = h.x + h.y + h.z + h.w;
        float sq = h.x * h.x + h.y * h.y + h.z * h.z + h.w * h.w;
        #pragma unroll
        for (int off = 32; off > 0; off >>= 1) {
            s  += __shfl_xor(s,  off, 64);
            sq += __shfl_xor(sq, off, 64);
        }
        const float mean = s * (1.0f / 256.0f);
        const float var  = fmaf(-mean, mean, sq * (1.0f / 256.0f));
        const float inv  = rsqrtf(var + 1e-5f);

        const float4 sv = (c < 5) ? s0v : s1v;
        float4 o;
        o.x = (fmaf((h.x - mean) * inv, gam.x, bta.x) + sv.x) * maskf;
        o.y = (fmaf((h.y - mean) * inv, gam.y, bta.y) + sv.y) * maskf;
        o.z = (fmaf((h.z - mean) * inv, gam.z, bta.z) + sv.z) * maskf;
        o.w = (fmaf((h.w - mean) * inv, gam.w, bta.w) + sv.w) * maskf;
        *reinterpret_cast<float4*>(out_emb + ((size_t)g * Cdim + c) * Ddim + d0) = o;
    }

    if (lane < Cdim)
        out_mask[(size_t)g * Cdim + lane] = maskf;
}

extern "C" void kernel_launch(void* const* d_in, const int* in_sizes, int n_in,
                              void* d_out, int out_size, void* d_ws, size_t ws_size,
                              hipStream_t stream)
{
    (void)in_sizes; (void)n_in; (void)d_ws; (void)ws_size; (void)out_size;

    const int*   card_ids    = (const int*)d_in[0];
    const int*   hero_pos    = (const int*)d_in[1];
    const int*   acting_pos  = (const int*)d_in[2];
    const int*   num_players = (const int*)d_in[3];
    const int*   seq_lengths = (const int*)d_in[4];
    const float* scalars     = (const float*)d_in[5];
    const float* bets        = (const float*)d_in[6];
    const float* action      = (const float*)d_in[7];
    const float* card_table  = (const float*)d_in[8];
    const float* source_tab  = (const float*)d_in[9];
    const float* hero_table  = (const float*)d_in[10];
    const float* acting_tab  = (const float*)d_in[11];
    const float* nump_table  = (const float*)d_in[12];
    const float* W_scalar    = (const float*)d_in[13];
    const float* b_scalar    = (const float*)d_in[14];
    const float* W_bet       = (const float*)d_in[15];
    const float* b_bet       = (const float*)d_in[16];
    const float* W_action    = (const float*)d_in[17];
    const float* b_action    = (const float*)d_in[18];
    const float* W_combine   = (const float*)d_in[19];
    const float* b_combine   = (const float*)d_in[20];
    const float* ln_gamma    = (const float*)d_in[21];
    const float* ln_beta     = (const float*)d_in[22];

    float* out_emb  = (float*)d_out;
    float* out_mask = out_emb + (size_t)Bdim * Edim * Cdim * Ddim;

    hipLaunchKernelGGL(precompute_tables, dim3(103), dim3(256), 0, stream,
                       card_table, hero_table, acting_tab, nump_table,
                       W_scalar, b_scalar, W_bet, b_bet, W_action, b_action,
                       W_combine);

    const int nEvents = Bdim * Edim;             // 8192
    hipLaunchKernelGGL(event_embed, dim3(nEvents / 4), dim3(256), 0, stream,
                       card_ids, hero_pos, acting_pos, num_players, seq_lengths,
                       scalars, bets, action, source_tab, b_combine,
                       ln_gamma, ln_beta, out_emb, out_mask);
}